// Round 1
// baseline (77204.700 us; speedup 1.0000x reference)
//
#include <hip/hip_runtime.h>
#include <hip/hip_fp16.h>

#define P_LEN 1000
#define Q_LEN 100
#define BATCH 128
#define D_IN 512
#define HID 256

typedef _Float16 f16x8 __attribute__((ext_vector_type(8)));
typedef _Float16 f16x2 __attribute__((ext_vector_type(2)));
typedef float f32x4 __attribute__((ext_vector_type(4)));

#define LOG2E 1.4426950408889634f

__device__ __forceinline__ float fexp2(float x) {
#if __has_builtin(__builtin_amdgcn_exp2f)
  return __builtin_amdgcn_exp2f(x);
#else
  return exp2f(x);
#endif
}
__device__ __forceinline__ float frcp(float x) {
#if __has_builtin(__builtin_amdgcn_rcpf)
  return __builtin_amdgcn_rcpf(x);
#else
  return 1.0f / x;
#endif
}
__device__ __forceinline__ float fast_tanh(float x) {
  // tanh(x) = (e^{2x}-1)/(e^{2x}+1); args are O(1) here, no overflow risk
  float t = fexp2(x * (2.0f * LOG2E));
  return (t - 1.0f) * frcp(t + 1.0f);
}
__device__ __forceinline__ float fast_sigmoid(float x) {
  return frcp(1.0f + fexp2(-x * LOG2E));
}

__device__ __forceinline__ float fdot2u(unsigned a, unsigned b, float c) {
#if __has_builtin(__builtin_amdgcn_fdot2)
  return __builtin_amdgcn_fdot2(__builtin_bit_cast(f16x2, a),
                                __builtin_bit_cast(f16x2, b), c, false);
#else
  __half2 ah = __builtin_bit_cast(__half2, a);
  __half2 bh = __builtin_bit_cast(__half2, b);
  float2 af = __half22float2(ah), bf = __half22float2(bh);
  return c + af.x * bf.x + af.y * bf.y;
#endif
}
// dot of 8 f16 pairs packed in uint4
__device__ __forceinline__ float dot8(uint4 w, uint4 v, float acc) {
  acc = fdot2u(w.x, v.x, acc);
  acc = fdot2u(w.y, v.y, acc);
  acc = fdot2u(w.z, v.z, acc);
  acc = fdot2u(w.w, v.w, acc);
  return acc;
}

// ---------------------------------------------------------------- convert
__global__ void cvt_f32_f16(const float* __restrict__ src, __half* __restrict__ dst, int n) {
  int i = blockIdx.x * blockDim.x + threadIdx.x;
  int stride = gridDim.x * blockDim.x;
  for (; i < n; i += stride) dst[i] = __float2half(src[i]);
}

// ---------------------------------------------------------------- GEMM
// C[m,n] = sum_k A[m,k] * W[n,k];  A fp32 [M,K] (converted on the fly), W f16 [N,K], C f16 [M,N]
#define BM 128
#define BN 64
#define BK 32
__global__ __launch_bounds__(256) void gemm_a32w16(const float* __restrict__ A,
                                                   const __half* __restrict__ W,
                                                   __half* __restrict__ C,
                                                   int M, int N, int K) {
  __shared__ __align__(16) __half As[BM][BK + 8];
  __shared__ __align__(16) __half Bs[BN][BK + 8];
  int t = threadIdx.x;
  int lane = t & 63, wave = t >> 6;
  int wm = wave >> 1, wn = wave & 1;     // 2x2 wave grid; wave tile 64x32
  int bm = blockIdx.x * BM, bn = blockIdx.y * BN;
  f32x4 acc[4][2] = {};
  int fr = lane & 15, fk = (lane >> 4) * 8, fq = lane >> 4;

  for (int kk = 0; kk < K; kk += BK) {
    {  // stage A: 128 rows x 32 cols, fp32 -> f16
      int r = t >> 1, c0 = (t & 1) * 16;
      const float* ap = A + (long)(bm + r) * K + kk + c0;
      float4 f0 = ((const float4*)ap)[0];
      float4 f1 = ((const float4*)ap)[1];
      float4 f2 = ((const float4*)ap)[2];
      float4 f3 = ((const float4*)ap)[3];
      __half2* dp = (__half2*)&As[r][c0];
      dp[0] = __float22half2_rn(make_float2(f0.x, f0.y));
      dp[1] = __float22half2_rn(make_float2(f0.z, f0.w));
      dp[2] = __float22half2_rn(make_float2(f1.x, f1.y));
      dp[3] = __float22half2_rn(make_float2(f1.z, f1.w));
      dp[4] = __float22half2_rn(make_float2(f2.x, f2.y));
      dp[5] = __float22half2_rn(make_float2(f2.z, f2.w));
      dp[6] = __float22half2_rn(make_float2(f3.x, f3.y));
      dp[7] = __float22half2_rn(make_float2(f3.z, f3.w));
    }
    {  // stage B: 64 rows x 32 cols, already f16
      int r = t >> 2, c0 = (t & 3) * 8;
      uint4 w = *(const uint4*)(W + (long)(bn + r) * K + kk + c0);
      *(uint4*)&Bs[r][c0] = w;
    }
    __syncthreads();
    f16x8 af[4], bf[2];
#pragma unroll
    for (int i = 0; i < 4; i++) af[i] = *(const f16x8*)&As[wm * 64 + i * 16 + fr][fk];
#pragma unroll
    for (int j = 0; j < 2; j++) bf[j] = *(const f16x8*)&Bs[wn * 32 + j * 16 + fr][fk];
#pragma unroll
    for (int i = 0; i < 4; i++)
#pragma unroll
      for (int j = 0; j < 2; j++)
        acc[i][j] = __builtin_amdgcn_mfma_f32_16x16x32_f16(af[i], bf[j], acc[i][j], 0, 0, 0);
    __syncthreads();
  }
#pragma unroll
  for (int i = 0; i < 4; i++)
#pragma unroll
    for (int j = 0; j < 2; j++)
#pragma unroll
      for (int r = 0; r < 4; r++) {
        int row = bm + wm * 64 + i * 16 + fq * 4 + r;
        int col = bn + wn * 32 + j * 16 + fr;
        C[(long)row * N + col] = __float2half(acc[i][j][r]);
      }
}

// ---------------------------------------------------------------- scan
// One workgroup per batch element b; 1024 threads; sequential over P steps.
__global__ __launch_bounds__(1024) void scan_kernel(const __half* __restrict__ Pp,   // [P*B, H]
                                                    const __half* __restrict__ Qp,   // [Q*B, H]
                                                    const __half* __restrict__ WvP,  // [H, H]
                                                    const __half* __restrict__ Whh,  // [3H, H]
                                                    const __half* __restrict__ Wg,   // [2H, 2H]
                                                    const __half* __restrict__ Wih,  // [3H, 2H]
                                                    const float* __restrict__ vT,    // [H]
                                                    float* __restrict__ out)         // [P*B, H]
{
  int b = blockIdx.x;
  int t = threadIdx.x;
  int wave = t >> 6, lane = t & 63;
  int g = lane >> 3, gl = lane & 7;  // 8-lane groups, one matrix row per group per round

  __shared__ __align__(16) __half s_prev_h[HID];
  __shared__ float s_prev_f[HID];
  __shared__ float s_lh[HID];
  __shared__ float s_hh[3 * HID];
  __shared__ float s_logits[Q_LEN];
  __shared__ float s_a[Q_LEN];
  __shared__ float s_red4[4][HID];
  __shared__ float s_uf[2 * HID];
  __shared__ __align__(16) __half s_utct[2 * HID];
  __shared__ float s_gv[2 * HID];
  __shared__ __align__(16) __half s_x[2 * HID];
  __shared__ float s_xg[3 * HID];

  if (t < HID) {
    s_prev_f[t] = 0.0f;
    s_prev_h[t] = __float2half(0.0f);
  }
  // per-lane attention constants: this lane always handles h = lane*4 .. lane*4+3
  int h0 = lane * 4;
  float vt0 = vT[h0 + 0], vt1 = vT[h0 + 1], vt2 = vT[h0 + 2], vt3 = vT[h0 + 3];
  __syncthreads();

  for (int p = 0; p < P_LEN; ++p) {
    const __half* pi_row = Pp + ((long)p * BATCH + b) * HID;

    // ---- phase 1: lh = WvP @ prev ; hh = W_hh @ prev   (K=256)
    {
      const uint4* v = (const uint4*)s_prev_h;  // 32 x uint4
#pragma unroll
      for (int rr = 0; rr < 2; ++rr) {
        int row = rr * 128 + wave * 8 + g;
        const uint4* wr = (const uint4*)(WvP + (long)row * HID);
        float a0 = 0.0f, a1 = 0.0f;
#pragma unroll
        for (int ps = 0; ps < 4; ps += 2) {
          a0 = dot8(wr[ps * 8 + gl], v[ps * 8 + gl], a0);
          a1 = dot8(wr[(ps + 1) * 8 + gl], v[(ps + 1) * 8 + gl], a1);
        }
        float acc = a0 + a1;
        acc += __shfl_xor(acc, 1);
        acc += __shfl_xor(acc, 2);
        acc += __shfl_xor(acc, 4);
        if (gl == 0) s_lh[row] = acc;
      }
#pragma unroll
      for (int rr = 0; rr < 6; ++rr) {
        int row = rr * 128 + wave * 8 + g;
        const uint4* wr = (const uint4*)(Whh + (long)row * HID);
        float a0 = 0.0f, a1 = 0.0f;
#pragma unroll
        for (int ps = 0; ps < 4; ps += 2) {
          a0 = dot8(wr[ps * 8 + gl], v[ps * 8 + gl], a0);
          a1 = dot8(wr[(ps + 1) * 8 + gl], v[(ps + 1) * 8 + gl], a1);
        }
        float acc = a0 + a1;
        acc += __shfl_xor(acc, 1);
        acc += __shfl_xor(acc, 2);
        acc += __shfl_xor(acc, 4);
        if (gl == 0) s_hh[row] = acc;
      }
    }
    __syncthreads();

    // ---- phase 2: logits[q] = sum_h vT[h] * tanh(Qp[q,b,h] + p_i[h] + lh[h])
    {
      uint2 piu = *(const uint2*)(pi_row + h0);
      float2 pa = __half22float2(__builtin_bit_cast(__half2, piu.x));
      float2 pb = __half22float2(__builtin_bit_cast(__half2, piu.y));
      float4 lh4 = *(const float4*)&s_lh[h0];
      float c0 = pa.x + lh4.x, c1 = pa.y + lh4.y, c2 = pb.x + lh4.z, c3 = pb.y + lh4.w;
      for (int q = wave; q < Q_LEN; q += 16) {
        uint2 qu = *(const uint2*)(Qp + ((long)q * BATCH + b) * HID + h0);
        float2 qa = __half22float2(__builtin_bit_cast(__half2, qu.x));
        float2 qb = __half22float2(__builtin_bit_cast(__half2, qu.y));
        float s = vt0 * fast_tanh(qa.x + c0) + vt1 * fast_tanh(qa.y + c1) +
                  vt2 * fast_tanh(qb.x + c2) + vt3 * fast_tanh(qb.y + c3);
        s += __shfl_xor(s, 1);
        s += __shfl_xor(s, 2);
        s += __shfl_xor(s, 4);
        s += __shfl_xor(s, 8);
        s += __shfl_xor(s, 16);
        s += __shfl_xor(s, 32);
        if (lane == 0) s_logits[q] = s;
      }
    }
    __syncthreads();

    // ---- softmax over q (wave 0 only; Q=100)
    if (wave == 0) {
      float x0 = s_logits[lane];
      float x1 = (lane < Q_LEN - 64) ? s_logits[lane + 64] : -1e30f;
      float m = fmaxf(x0, x1);
      m = fmaxf(m, __shfl_xor(m, 1));
      m = fmaxf(m, __shfl_xor(m, 2));
      m = fmaxf(m, __shfl_xor(m, 4));
      m = fmaxf(m, __shfl_xor(m, 8));
      m = fmaxf(m, __shfl_xor(m, 16));
      m = fmaxf(m, __shfl_xor(m, 32));
      float e0 = fexp2((x0 - m) * LOG2E);
      float e1 = (lane < Q_LEN - 64) ? fexp2((x1 - m) * LOG2E) : 0.0f;
      float ssum = e0 + e1;
      ssum += __shfl_xor(ssum, 1);
      ssum += __shfl_xor(ssum, 2);
      ssum += __shfl_xor(ssum, 4);
      ssum += __shfl_xor(ssum, 8);
      ssum += __shfl_xor(ssum, 16);
      ssum += __shfl_xor(ssum, 32);
      float inv = 1.0f / ssum;  // once per step, full-precision divide
      s_a[lane] = e0 * inv;
      if (lane < Q_LEN - 64) s_a[lane + 64] = e1 * inv;
    }
    __syncthreads();

    // ---- phase 3: ct[h] = sum_q a[q] * Qp[q,b,h]  (4-way q-split partials)
    {
      int h = t & 255, grp = t >> 8;
      int q0 = grp * 25;
      float acc = 0.0f;
#pragma unroll
      for (int q = q0; q < q0 + 25; ++q) {
        float qv = __half2float(Qp[((long)q * BATCH + b) * HID + h]);
        acc = fmaf(s_a[q], qv, acc);
      }
      s_red4[grp][h] = acc;
    }
    __syncthreads();

    // ---- combine ct; build utct = [p_i, ct]
    if (t < HID) {
      float ct = s_red4[0][t] + s_red4[1][t] + s_red4[2][t] + s_red4[3][t];
      float pi = __half2float(pi_row[t]);
      s_uf[t] = pi;
      s_uf[HID + t] = ct;
      s_utct[t] = __float2half(pi);
      s_utct[HID + t] = __float2half(ct);
    }
    __syncthreads();

    // ---- phase 4: gv = Wg @ utct  (512 rows, K=512)
    {
      const uint4* v = (const uint4*)s_utct;  // 64 x uint4
#pragma unroll
      for (int rr = 0; rr < 4; ++rr) {
        int row = rr * 128 + wave * 8 + g;
        const uint4* wr = (const uint4*)(Wg + (long)row * (2 * HID));
        float a0 = 0.0f, a1 = 0.0f;
#pragma unroll
        for (int ps = 0; ps < 8; ps += 2) {
          a0 = dot8(wr[ps * 8 + gl], v[ps * 8 + gl], a0);
          a1 = dot8(wr[(ps + 1) * 8 + gl], v[(ps + 1) * 8 + gl], a1);
        }
        float acc = a0 + a1;
        acc += __shfl_xor(acc, 1);
        acc += __shfl_xor(acc, 2);
        acc += __shfl_xor(acc, 4);
        if (gl == 0) s_gv[row] = acc;
      }
    }
    __syncthreads();
    if (t < 2 * HID) {
      float xv = s_uf[t] * fast_sigmoid(s_gv[t]);
      s_x[t] = __float2half(xv);
    }
    __syncthreads();

    // ---- phase 5: xg = W_ih @ x  (768 rows, K=512)
    {
      const uint4* v = (const uint4*)s_x;
#pragma unroll
      for (int rr = 0; rr < 6; ++rr) {
        int row = rr * 128 + wave * 8 + g;
        const uint4* wr = (const uint4*)(Wih + (long)row * (2 * HID));
        float a0 = 0.0f, a1 = 0.0f;
#pragma unroll
        for (int ps = 0; ps < 8; ps += 2) {
          a0 = dot8(wr[ps * 8 + gl], v[ps * 8 + gl], a0);
          a1 = dot8(wr[(ps + 1) * 8 + gl], v[(ps + 1) * 8 + gl], a1);
        }
        float acc = a0 + a1;
        acc += __shfl_xor(acc, 1);
        acc += __shfl_xor(acc, 2);
        acc += __shfl_xor(acc, 4);
        if (gl == 0) s_xg[row] = acc;
      }
    }
    __syncthreads();

    // ---- phase 6: GRU combine (torch gate order r,z,n), write h
    if (t < HID) {
      float r = fast_sigmoid(s_xg[t] + s_hh[t]);
      float z = fast_sigmoid(s_xg[HID + t] + s_hh[HID + t]);
      float n = fast_tanh(s_xg[2 * HID + t] + r * s_hh[2 * HID + t]);
      float h = (1.0f - z) * n + z * s_prev_f[t];
      out[((long)p * BATCH + b) * HID + t] = h;
      s_prev_f[t] = h;
      s_prev_h[t] = __float2half(h);
    }
    __syncthreads();
  }
}

// ---------------------------------------------------------------- launch
extern "C" void kernel_launch(void* const* d_in, const int* in_sizes, int n_in,
                              void* d_out, int out_size, void* d_ws, size_t ws_size,
                              hipStream_t stream) {
  const float* passage  = (const float*)d_in[0];   // [P,B,D]
  const float* question = (const float*)d_in[1];   // [Q,B,D]
  const float* vT  = (const float*)d_in[4];        // [H]
  const float* WuQ = (const float*)d_in[5];        // [H,D]
  const float* WuP = (const float*)d_in[6];        // [H,D]
  const float* WvP = (const float*)d_in[7];        // [H,H]
  const float* Wg  = (const float*)d_in[8];        // [2H,2H]
  const float* Wih = (const float*)d_in[9];        // [3H,2H]
  const float* Whh = (const float*)d_in[10];       // [3H,H]
  float* out = (float*)d_out;

  // workspace layout (all f16)
  __half* Pp16  = (__half*)d_ws;                                   // P*B*H
  __half* Qp16  = Pp16 + (size_t)P_LEN * BATCH * HID;              // Q*B*H
  __half* WuQ16 = Qp16 + (size_t)Q_LEN * BATCH * HID;              // H*D
  __half* WuP16 = WuQ16 + (size_t)HID * D_IN;                      // H*D
  __half* WvP16 = WuP16 + (size_t)HID * D_IN;                      // H*H
  __half* Wg16  = WvP16 + (size_t)HID * HID;                       // 2H*2H
  __half* Wih16 = Wg16 + (size_t)2 * HID * 2 * HID;                // 3H*2H
  __half* Whh16 = Wih16 + (size_t)3 * HID * 2 * HID;               // 3H*H

  cvt_f32_f16<<<64, 256, 0, stream>>>(WuQ, WuQ16, HID * D_IN);
  cvt_f32_f16<<<64, 256, 0, stream>>>(WuP, WuP16, HID * D_IN);
  cvt_f32_f16<<<32, 256, 0, stream>>>(WvP, WvP16, HID * HID);
  cvt_f32_f16<<<64, 256, 0, stream>>>(Wg, Wg16, 2 * HID * 2 * HID);
  cvt_f32_f16<<<64, 256, 0, stream>>>(Wih, Wih16, 3 * HID * 2 * HID);
  cvt_f32_f16<<<64, 256, 0, stream>>>(Whh, Whh16, 3 * HID * HID);

  // Qp = question @ WuQ^T   [Q*B, H]
  gemm_a32w16<<<dim3(Q_LEN * BATCH / BM, HID / BN), 256, 0, stream>>>(
      question, WuQ16, Qp16, Q_LEN * BATCH, HID, D_IN);
  // Pp = passage @ WuP^T    [P*B, H]
  gemm_a32w16<<<dim3(P_LEN * BATCH / BM, HID / BN), 256, 0, stream>>>(
      passage, WuP16, Pp16, P_LEN * BATCH, HID, D_IN);

  scan_kernel<<<BATCH, 1024, 0, stream>>>(Pp16, Qp16, WvP16, Whh16, Wg16, Wih16, vT, out);
}

// Round 2
// 50618.033 us; speedup vs baseline: 1.5252x; 1.5252x over previous
//
#include <hip/hip_runtime.h>
#include <hip/hip_fp16.h>

#define P_LEN 1000
#define Q_LEN 100
#define BATCH 128
#define D_IN 512
#define HID 256

#define NGROUP 4
#define WPG 32   // workgroups per group
#define BPG 32   // batches per group
#define NTHR 256

typedef _Float16 f16x8 __attribute__((ext_vector_type(8)));
typedef _Float16 f16x2 __attribute__((ext_vector_type(2)));
typedef float f32x4 __attribute__((ext_vector_type(4)));

#define LOG2E 1.4426950408889634f

__device__ __forceinline__ float fexp2(float x) {
#if __has_builtin(__builtin_amdgcn_exp2f)
  return __builtin_amdgcn_exp2f(x);
#else
  return exp2f(x);
#endif
}
__device__ __forceinline__ float frcp(float x) {
#if __has_builtin(__builtin_amdgcn_rcpf)
  return __builtin_amdgcn_rcpf(x);
#else
  return 1.0f / x;
#endif
}
__device__ __forceinline__ float fast_tanh(float x) {
  float t = fexp2(x * (2.0f * LOG2E));
  return (t - 1.0f) * frcp(t + 1.0f);
}
__device__ __forceinline__ float fast_sigmoid(float x) {
  return frcp(1.0f + fexp2(-x * LOG2E));
}

// ---------------------------------------------------------------- convert
__global__ void cvt_f32_f16(const float* __restrict__ src, __half* __restrict__ dst, int n) {
  int i = blockIdx.x * blockDim.x + threadIdx.x;
  int stride = gridDim.x * blockDim.x;
  for (; i < n; i += stride) dst[i] = __float2half(src[i]);
}

// ---------------------------------------------------------------- GEMM (precompute Qp/Pp)
#define BM 128
#define BN 64
#define BK 32
__global__ __launch_bounds__(256) void gemm_a32w16(const float* __restrict__ A,
                                                   const __half* __restrict__ W,
                                                   __half* __restrict__ C,
                                                   int M, int N, int K) {
  __shared__ __align__(16) __half As[BM][BK + 8];
  __shared__ __align__(16) __half Bs[BN][BK + 8];
  int t = threadIdx.x;
  int lane = t & 63, wave = t >> 6;
  int wm = wave >> 1, wn = wave & 1;
  int bm = blockIdx.x * BM, bn = blockIdx.y * BN;
  f32x4 acc[4][2] = {};
  int fr = lane & 15, fk = (lane >> 4) * 8, fq = lane >> 4;

  for (int kk = 0; kk < K; kk += BK) {
    {
      int r = t >> 1, c0 = (t & 1) * 16;
      const float* ap = A + (long)(bm + r) * K + kk + c0;
      float4 f0 = ((const float4*)ap)[0];
      float4 f1 = ((const float4*)ap)[1];
      float4 f2 = ((const float4*)ap)[2];
      float4 f3 = ((const float4*)ap)[3];
      __half2* dp = (__half2*)&As[r][c0];
      dp[0] = __float22half2_rn(make_float2(f0.x, f0.y));
      dp[1] = __float22half2_rn(make_float2(f0.z, f0.w));
      dp[2] = __float22half2_rn(make_float2(f1.x, f1.y));
      dp[3] = __float22half2_rn(make_float2(f1.z, f1.w));
      dp[4] = __float22half2_rn(make_float2(f2.x, f2.y));
      dp[5] = __float22half2_rn(make_float2(f2.z, f2.w));
      dp[6] = __float22half2_rn(make_float2(f3.x, f3.y));
      dp[7] = __float22half2_rn(make_float2(f3.z, f3.w));
    }
    {
      int r = t >> 2, c0 = (t & 3) * 8;
      uint4 w = *(const uint4*)(W + (long)(bn + r) * K + kk + c0);
      *(uint4*)&Bs[r][c0] = w;
    }
    __syncthreads();
    f16x8 af[4], bf[2];
#pragma unroll
    for (int i = 0; i < 4; i++) af[i] = *(const f16x8*)&As[wm * 64 + i * 16 + fr][fk];
#pragma unroll
    for (int j = 0; j < 2; j++) bf[j] = *(const f16x8*)&Bs[wn * 32 + j * 16 + fr][fk];
#pragma unroll
    for (int i = 0; i < 4; i++)
#pragma unroll
      for (int j = 0; j < 2; j++)
        acc[i][j] = __builtin_amdgcn_mfma_f32_16x16x32_f16(af[i], bf[j], acc[i][j], 0, 0, 0);
    __syncthreads();
  }
#pragma unroll
  for (int i = 0; i < 4; i++)
#pragma unroll
    for (int j = 0; j < 2; j++)
#pragma unroll
      for (int r = 0; r < 4; r++) {
        int row = bm + wm * 64 + i * 16 + fq * 4 + r;
        int col = bn + wn * 32 + j * 16 + fr;
        C[(long)row * N + col] = __float2half(acc[i][j][r]);
      }
}

// ---------------------------------------------------------------- group barrier
__device__ __forceinline__ void group_barrier(unsigned* cnt, unsigned target) {
  __syncthreads();
  if (threadIdx.x == 0) {
    __threadfence();  // release our writes (L2 writeback, device scope)
    __hip_atomic_fetch_add(cnt, 1u, __ATOMIC_RELEASE, __HIP_MEMORY_SCOPE_AGENT);
    while (__hip_atomic_load(cnt, __ATOMIC_RELAXED, __HIP_MEMORY_SCOPE_AGENT) < target) {
      __builtin_amdgcn_s_sleep(1);
    }
    __threadfence();  // acquire (invalidate stale L1/L2 lines)
  }
  __syncthreads();
}

// ---------------------------------------------------------------- cooperative scan
// 4 groups x 32 WGs x 256 threads. Each WG holds a row-slice of all weights in
// LDS for the whole scan; per-step GEMVs become M=32 batched MFMA GEMMs.
// Group-shared activations live in L2-cached global buffers; 4 barriers/step.
__global__ __launch_bounds__(256) void scan_coop(
    const __half* __restrict__ Pp, const __half* __restrict__ Qp,
    const __half* __restrict__ WvP, const __half* __restrict__ Whh,
    const __half* __restrict__ Wg, const __half* __restrict__ Wih,
    const float* __restrict__ vT, float* __restrict__ out,
    float* __restrict__ Y1b,   // [G][32][1024] f32: cols 0..255 lh, 256.. hh(r,z,n)
    float* __restrict__ uFb,   // [G][32][512]  f32 utct
    __half* __restrict__ uHb,  // [G][32][512]  f16 utct
    __half* __restrict__ xHb,  // [G][32][512]  f16 x
    float* __restrict__ pFb,   // [G][32][256]  f32 prev
    __half* __restrict__ pHb,  // [G][32][256]  f16 prev
    unsigned* __restrict__ bars)  // [G][64] counters (1 line/group)
{
  const int bid = blockIdx.x;
  const int g = bid >> 5;
  const int w = bid & 31;
  const int t = threadIdx.x;
  const int lane = t & 63, wave = t >> 6;
  const int fr = lane & 15, fq = lane >> 4;
  const int fk = fq * 8;

  float* Y1 = Y1b + (size_t)g * BPG * 1024;
  float* uF = uFb + (size_t)g * BPG * 512;
  __half* uH = uHb + (size_t)g * BPG * 512;
  __half* xH = xHb + (size_t)g * BPG * 512;
  float* pF = pFb + (size_t)g * BPG * 256;
  __half* pH = pHb + (size_t)g * BPG * 256;
  unsigned* cnt = bars + g * 64;

  // LDS: 16384 + 16384 + 24576 + 4096 + 400 + 400 = 62,240 B
  __shared__ __align__(16) __half sW1[32][256];   // slots: 0..7 WvP rows w*8+s; 8..31 Whh gate rows
  __shared__ __align__(16) __half sWg[16][512];   // Wg rows w*16+s
  __shared__ __align__(16) __half sW3[24][512];   // Wih gate rows (8 per gate at jj=w*8..)
  __shared__ __align__(16) float scratch[1024];   // phase2 ct partials / gemm3 xg staging
  __shared__ float s_logits[Q_LEN];
  __shared__ float s_a[Q_LEN];

  // ---- load resident weight slices
  for (int i = t; i < 32 * 32; i += NTHR) {       // sW1: 32 slots x 32 uint4
    int slot = i >> 5, off = (i & 31) * 8;
    const __half* src;
    if (slot < 8) src = WvP + (size_t)(w * 8 + slot) * 256;
    else {
      int gate = (slot - 8) >> 3, jl = (slot - 8) & 7;
      src = Whh + (size_t)(gate * 256 + w * 8 + jl) * 256;
    }
    *(uint4*)&sW1[slot][off] = *(const uint4*)(src + off);
  }
  for (int i = t; i < 16 * 64; i += NTHR) {       // sWg
    int s = i >> 6, off = (i & 63) * 8;
    *(uint4*)&sWg[s][off] = *(const uint4*)(Wg + (size_t)(w * 16 + s) * 512 + off);
  }
  for (int i = t; i < 24 * 64; i += NTHR) {       // sW3
    int s = i >> 6, off = (i & 63) * 8;
    int gate = s >> 3, jl = s & 7;
    *(uint4*)&sW3[s][off] = *(const uint4*)(Wih + (size_t)(gate * 256 + w * 8 + jl) * 512 + off);
  }

  const int bg_att = g * BPG + w;   // this WG's batch for the attention phase
  const int h0 = lane * 4;
  float vt0 = vT[h0], vt1 = vT[h0 + 1], vt2 = vT[h0 + 2], vt3 = vT[h0 + 3];
  __syncthreads();

  unsigned target = 0;

  for (int p = 0; p < P_LEN; ++p) {
    // ---------------- GEMM1: Y1[b][col] = [WvP;Whh] @ prev   (M=32,N=32,K=256)
    {
      const int mt = wave >> 1, nt = wave & 1;
      const __half* arow = pH + (mt * 16 + fr) * 256;
      f32x4 acc = {0.f, 0.f, 0.f, 0.f};
#pragma unroll
      for (int kc = 0; kc < 8; ++kc) {
        f16x8 af = *(const f16x8*)(arow + kc * 32 + fk);
        f16x8 bf = *(const f16x8*)&sW1[nt * 16 + fr][kc * 32 + fk];
        acc = __builtin_amdgcn_mfma_f32_16x16x32_f16(af, bf, acc, 0, 0, 0);
      }
      int slot = nt * 16 + fr;
      int col = (slot < 8) ? (w * 8 + slot)
                           : (256 + ((slot - 8) >> 3) * 256 + w * 8 + ((slot - 8) & 7));
#pragma unroll
      for (int r = 0; r < 4; ++r) {
        int b = mt * 16 + fq * 4 + r;
        Y1[b * 1024 + col] = acc[r];
      }
    }
    target += WPG; group_barrier(cnt, target);

    // ---------------- phase 2: attention for b = w
    {
      const __half* pi_row = Pp + ((size_t)p * BATCH + bg_att) * 256;
      uint2 piu = *(const uint2*)(pi_row + h0);
      float2 pa = __half22float2(__builtin_bit_cast(__half2, piu.x));
      float2 pb = __half22float2(__builtin_bit_cast(__half2, piu.y));
      float4 lh4 = *(const float4*)&Y1[w * 1024 + h0];
      float c0 = pa.x + lh4.x, c1 = pa.y + lh4.y, c2 = pb.x + lh4.z, c3 = pb.y + lh4.w;
      for (int q = wave; q < Q_LEN; q += 4) {
        uint2 qu = *(const uint2*)(Qp + ((size_t)q * BATCH + bg_att) * 256 + h0);
        float2 qa = __half22float2(__builtin_bit_cast(__half2, qu.x));
        float2 qb = __half22float2(__builtin_bit_cast(__half2, qu.y));
        float s = vt0 * fast_tanh(qa.x + c0) + vt1 * fast_tanh(qa.y + c1) +
                  vt2 * fast_tanh(qb.x + c2) + vt3 * fast_tanh(qb.y + c3);
        s += __shfl_xor(s, 1);
        s += __shfl_xor(s, 2);
        s += __shfl_xor(s, 4);
        s += __shfl_xor(s, 8);
        s += __shfl_xor(s, 16);
        s += __shfl_xor(s, 32);
        if (lane == 0) s_logits[q] = s;
      }
      __syncthreads();
      if (wave == 0) {  // softmax over q
        float x0 = s_logits[lane];
        float x1 = (lane < Q_LEN - 64) ? s_logits[lane + 64] : -1e30f;
        float m = fmaxf(x0, x1);
        m = fmaxf(m, __shfl_xor(m, 1));
        m = fmaxf(m, __shfl_xor(m, 2));
        m = fmaxf(m, __shfl_xor(m, 4));
        m = fmaxf(m, __shfl_xor(m, 8));
        m = fmaxf(m, __shfl_xor(m, 16));
        m = fmaxf(m, __shfl_xor(m, 32));
        float e0 = fexp2((x0 - m) * LOG2E);
        float e1 = (lane < Q_LEN - 64) ? fexp2((x1 - m) * LOG2E) : 0.0f;
        float ssum = e0 + e1;
        ssum += __shfl_xor(ssum, 1);
        ssum += __shfl_xor(ssum, 2);
        ssum += __shfl_xor(ssum, 4);
        ssum += __shfl_xor(ssum, 8);
        ssum += __shfl_xor(ssum, 16);
        ssum += __shfl_xor(ssum, 32);
        float inv = 1.0f / ssum;
        s_a[lane] = e0 * inv;
        if (lane < Q_LEN - 64) s_a[lane + 64] = e1 * inv;
      }
      __syncthreads();
      // ct partials: each wave sums its q's
      float a0 = 0.f, a1 = 0.f, a2 = 0.f, a3 = 0.f;
      for (int q = wave; q < Q_LEN; q += 4) {
        float aq = s_a[q];
        uint2 qu = *(const uint2*)(Qp + ((size_t)q * BATCH + bg_att) * 256 + h0);
        float2 qa = __half22float2(__builtin_bit_cast(__half2, qu.x));
        float2 qb = __half22float2(__builtin_bit_cast(__half2, qu.y));
        a0 = fmaf(aq, qa.x, a0);
        a1 = fmaf(aq, qa.y, a1);
        a2 = fmaf(aq, qb.x, a2);
        a3 = fmaf(aq, qb.y, a3);
      }
      *(float4*)&scratch[wave * 256 + h0] = make_float4(a0, a1, a2, a3);
      __syncthreads();
      {
        float ct = scratch[t] + scratch[256 + t] + scratch[512 + t] + scratch[768 + t];
        float pi = __half2float(pi_row[t]);
        uF[w * 512 + t] = pi;
        uF[w * 512 + 256 + t] = ct;
        uH[w * 512 + t] = __float2half(pi);
        uH[w * 512 + 256 + t] = __float2half(ct);
      }
    }
    target += WPG; group_barrier(cnt, target);

    // ---------------- GEMM2: gv = Wg@utct; x = utct * sigmoid(gv)  (M=32,N=16,K=512)
    if (wave < 2) {
      const int mt = wave;
      const __half* arow = uH + (mt * 16 + fr) * 512;
      f32x4 acc = {0.f, 0.f, 0.f, 0.f};
#pragma unroll
      for (int kc = 0; kc < 16; ++kc) {
        f16x8 af = *(const f16x8*)(arow + kc * 32 + fk);
        f16x8 bf = *(const f16x8*)&sWg[fr][kc * 32 + fk];
        acc = __builtin_amdgcn_mfma_f32_16x16x32_f16(af, bf, acc, 0, 0, 0);
      }
      int j = w * 16 + fr;
#pragma unroll
      for (int r = 0; r < 4; ++r) {
        int b = mt * 16 + fq * 4 + r;
        float ufv = uF[b * 512 + j];
        xH[b * 512 + j] = __float2half(ufv * fast_sigmoid(acc[r]));
      }
    }
    target += WPG; group_barrier(cnt, target);

    // ---------------- GEMM3: xg = Wih@x (M=32,N=24,K=512) + GRU combine
    {
      const int mt = wave >> 1, nt = wave & 1;
      const __half* arow = xH + (mt * 16 + fr) * 512;
      int slot = nt * 16 + fr;
      int srow = slot < 24 ? slot : 23;  // clamp pad slots (outputs unused)
      f32x4 acc = {0.f, 0.f, 0.f, 0.f};
#pragma unroll
      for (int kc = 0; kc < 16; ++kc) {
        f16x8 af = *(const f16x8*)(arow + kc * 32 + fk);
        f16x8 bf = *(const f16x8*)&sW3[srow][kc * 32 + fk];
        acc = __builtin_amdgcn_mfma_f32_16x16x32_f16(af, bf, acc, 0, 0, 0);
      }
      if (slot < 24) {
#pragma unroll
        for (int r = 0; r < 4; ++r) {
          int b = mt * 16 + fq * 4 + r;
          scratch[b * 24 + slot] = acc[r];
        }
      }
      __syncthreads();
      {
        int b = t >> 3, jl = t & 7;
        int jj = w * 8 + jl;
        float xr = scratch[b * 24 + jl];
        float xz = scratch[b * 24 + 8 + jl];
        float xn = scratch[b * 24 + 16 + jl];
        float hr = Y1[b * 1024 + 256 + jj];
        float hz = Y1[b * 1024 + 512 + jj];
        float hn = Y1[b * 1024 + 768 + jj];
        float pv = pF[b * 256 + jj];
        float r = fast_sigmoid(xr + hr);
        float z = fast_sigmoid(xz + hz);
        float n = fast_tanh(xn + r * hn);
        float h = (1.0f - z) * n + z * pv;
        int bgl = g * BPG + b;
        out[((size_t)p * BATCH + bgl) * 256 + jj] = h;
        pF[b * 256 + jj] = h;
        pH[b * 256 + jj] = __float2half(h);
      }
    }
    target += WPG; group_barrier(cnt, target);
  }
}

// ---------------------------------------------------------------- launch
extern "C" void kernel_launch(void* const* d_in, const int* in_sizes, int n_in,
                              void* d_out, int out_size, void* d_ws, size_t ws_size,
                              hipStream_t stream) {
  const float* passage  = (const float*)d_in[0];
  const float* question = (const float*)d_in[1];
  const float* vT  = (const float*)d_in[4];
  const float* WuQ = (const float*)d_in[5];
  const float* WuP = (const float*)d_in[6];
  const float* WvP = (const float*)d_in[7];
  const float* Wg  = (const float*)d_in[8];
  const float* Wih = (const float*)d_in[9];
  const float* Whh = (const float*)d_in[10];
  float* out = (float*)d_out;

  char* base = (char*)d_ws;
  size_t off = 0;
  auto alloc = [&](size_t bytes) {
    char* p = base + off;
    off = (off + bytes + 255) & ~(size_t)255;
    return p;
  };
  __half* Pp16  = (__half*)alloc((size_t)P_LEN * BATCH * HID * 2);
  __half* Qp16  = (__half*)alloc((size_t)Q_LEN * BATCH * HID * 2);
  __half* WuQ16 = (__half*)alloc((size_t)HID * D_IN * 2);
  __half* WuP16 = (__half*)alloc((size_t)HID * D_IN * 2);
  __half* WvP16 = (__half*)alloc((size_t)HID * HID * 2);
  __half* Wg16  = (__half*)alloc((size_t)2 * HID * 2 * HID * 2);
  __half* Wih16 = (__half*)alloc((size_t)3 * HID * 2 * HID * 2);
  __half* Whh16 = (__half*)alloc((size_t)3 * HID * HID * 2);
  float*  Y1b   = (float*)alloc((size_t)NGROUP * BPG * 1024 * 4);
  float*  uFb   = (float*)alloc((size_t)NGROUP * BPG * 512 * 4);
  __half* uHb   = (__half*)alloc((size_t)NGROUP * BPG * 512 * 2);
  __half* xHb   = (__half*)alloc((size_t)NGROUP * BPG * 512 * 2);
  // zero-region: prev f32, prev f16, barrier counters (contiguous)
  char* zbase = base + off;
  float*  pFb   = (float*)alloc((size_t)NGROUP * BPG * 256 * 4);
  __half* pHb   = (__half*)alloc((size_t)NGROUP * BPG * 256 * 2);
  unsigned* bars = (unsigned*)alloc((size_t)NGROUP * 64 * 4);
  size_t zbytes = (base + off) - zbase;

  hipMemsetAsync(zbase, 0, zbytes, stream);

  cvt_f32_f16<<<64, 256, 0, stream>>>(WuQ, WuQ16, HID * D_IN);
  cvt_f32_f16<<<64, 256, 0, stream>>>(WuP, WuP16, HID * D_IN);
  cvt_f32_f16<<<32, 256, 0, stream>>>(WvP, WvP16, HID * HID);
  cvt_f32_f16<<<64, 256, 0, stream>>>(Wg, Wg16, 2 * HID * 2 * HID);
  cvt_f32_f16<<<64, 256, 0, stream>>>(Wih, Wih16, 3 * HID * 2 * HID);
  cvt_f32_f16<<<64, 256, 0, stream>>>(Whh, Whh16, 3 * HID * HID);

  gemm_a32w16<<<dim3(Q_LEN * BATCH / BM, HID / BN), 256, 0, stream>>>(
      question, WuQ16, Qp16, Q_LEN * BATCH, HID, D_IN);
  gemm_a32w16<<<dim3(P_LEN * BATCH / BM, HID / BN), 256, 0, stream>>>(
      passage, WuP16, Pp16, P_LEN * BATCH, HID, D_IN);

  scan_coop<<<NGROUP * WPG, NTHR, 0, stream>>>(
      Pp16, Qp16, WvP16, Whh16, Wg16, Wih16, vT, out,
      Y1b, uFb, uHb, xHb, pFb, pHb, bars);
}